// Round 8
// baseline (550.689 us; speedup 1.0000x reference)
//
#include <hip/hip_runtime.h>

#define NN 16384
#define NC 64
#define NE 524288
#define ALPHA 0.9f
#define KSTEPS 10

typedef _Float16 f16;
typedef _Float16 f16x4 __attribute__((ext_vector_type(4)));
typedef _Float16 f16x8 __attribute__((ext_vector_type(8)));
typedef float f32x4 __attribute__((ext_vector_type(4)));
typedef int i32x16 __attribute__((ext_vector_type(16)));

#define MEMB   asm volatile("" ::: "memory")
#define SCHED0 __builtin_amdgcn_sched_barrier(0)

// ---------------- degree count ----------------
__global__ __launch_bounds__(256) void deg_kernel(const int* __restrict__ dst,
                                                  unsigned* __restrict__ deg) {
    int e = blockIdx.x * 256 + threadIdx.x;
    atomicAdd(&deg[dst[e]], 1u);
}

// ------------- dinv + PADDED exclusive scan + cursor init (single block) -------------
__global__ __launch_bounds__(1024) void scan_kernel(const unsigned* __restrict__ deg,
                                                    float* __restrict__ dinv,
                                                    unsigned* __restrict__ rowoff,
                                                    unsigned* __restrict__ cursor) {
    __shared__ unsigned part[1024];
    const int t = threadIdx.x;
    const int base = t * 16;
    unsigned local[16];
    unsigned s = 0;
    #pragma unroll
    for (int i = 0; i < 16; ++i) {
        local[i] = s;
        s += (deg[base + i] + 15u) & ~15u;
    }
    part[t] = s;
    __syncthreads();
    for (int off = 1; off < 1024; off <<= 1) {
        unsigned v = (t >= off) ? part[t - off] : 0u;
        __syncthreads();
        part[t] += v;
        __syncthreads();
    }
    const unsigned ex = (t == 0) ? 0u : part[t - 1];
    #pragma unroll
    for (int i = 0; i < 16; ++i) {
        unsigned ro = ex + local[i];
        rowoff[base + i] = ro;
        cursor[base + i] = ro;
        unsigned d = deg[base + i];
        dinv[base + i] = rsqrtf(fmaxf((float)d, 1.0f));
    }
    if (t == 1023) rowoff[NN] = part[1023];
}

// ---------------- CSR fill (src, w packed as int2; pads pre-zeroed) ----------------
__global__ __launch_bounds__(256) void fill_kernel(const int* __restrict__ src,
                                                   const int* __restrict__ dst,
                                                   const float* __restrict__ dinv,
                                                   unsigned* __restrict__ cursor,
                                                   int2* __restrict__ csr) {
    int e = blockIdx.x * 256 + threadIdx.x;
    int s = src[e], d = dst[e];
    float w = dinv[s] * dinv[d];
    unsigned p = atomicAdd(&cursor[d], 1u);
    csr[p] = make_int2(s, __float_as_int(w));
}

// ---------------- propagation step: y = a*A@x + (1-a)*x ----------------
__global__ __launch_bounds__(256) void prop_kernel(const float* __restrict__ x,
                                                   float* __restrict__ y,
                                                   const unsigned* __restrict__ rowoff,
                                                   const int* __restrict__ csr) {
    const int lane = threadIdx.x & 63;
    const int n = __builtin_amdgcn_readfirstlane(blockIdx.x * 4 + (threadIdx.x >> 6));
    const unsigned beg = rowoff[n];
    const unsigned np = (rowoff[n + 1] - beg) >> 4;   // pairs of 8-edge batches
    float acc0 = 0.f, acc1 = 0.f;
    if (np) {
        i32x16 e0 = *(const i32x16*)(csr + 2 * beg);
        i32x16 e1 = *(const i32x16*)(csr + 2 * beg + 16);
        float xv0[8], xv1[8];
        #pragma unroll
        for (int j = 0; j < 8; ++j) xv0[j] = x[(unsigned)e0[2 * j] * 64u + lane];
        #pragma unroll
        for (int j = 0; j < 8; ++j) xv1[j] = x[(unsigned)e1[2 * j] * 64u + lane];
        for (unsigned p = 1; p < np; ++p) {
            const i32x16 f0 = *(const i32x16*)(csr + 2 * (beg + p * 16));
            const i32x16 f1 = *(const i32x16*)(csr + 2 * (beg + p * 16) + 16);
            #pragma unroll
            for (int j = 0; j < 8; ++j) {
                const float w = __int_as_float(e0[2 * j + 1]);
                if (j & 1) acc1 = fmaf(w, xv0[j], acc1);
                else       acc0 = fmaf(w, xv0[j], acc0);
            }
            #pragma unroll
            for (int j = 0; j < 8; ++j) xv0[j] = x[(unsigned)f0[2 * j] * 64u + lane];
            #pragma unroll
            for (int j = 0; j < 8; ++j) {
                const float w = __int_as_float(e1[2 * j + 1]);
                if (j & 1) acc1 = fmaf(w, xv1[j], acc1);
                else       acc0 = fmaf(w, xv1[j], acc0);
            }
            #pragma unroll
            for (int j = 0; j < 8; ++j) xv1[j] = x[(unsigned)f1[2 * j] * 64u + lane];
            e0 = f0; e1 = f1;
        }
        #pragma unroll
        for (int j = 0; j < 8; ++j) {
            const float w = __int_as_float(e0[2 * j + 1]);
            if (j & 1) acc1 = fmaf(w, xv0[j], acc1);
            else       acc0 = fmaf(w, xv0[j], acc0);
        }
        #pragma unroll
        for (int j = 0; j < 8; ++j) {
            const float w = __int_as_float(e1[2 * j + 1]);
            if (j & 1) acc1 = fmaf(w, xv1[j], acc1);
            else       acc0 = fmaf(w, xv1[j], acc0);
        }
    }
    y[n * 64 + lane] = ALPHA * (acc0 + acc1) + (1.0f - ALPHA) * x[n * 64 + lane];
}

// ---------------- y split: y[16384][64] f32 -> yhT, ylT [64][16384] f16 ----------------
__global__ __launch_bounds__(256) void ysplit_kernel(const float* __restrict__ y,
                                                     f16* __restrict__ yhT,
                                                     f16* __restrict__ ylT) {
    __shared__ f16 hb[64][72];
    __shared__ f16 lb[64][72];
    const int t = threadIdx.x;
    const int b = blockIdx.x;            // k chunk [b*64, b*64+64)
    const int kl = t >> 2;               // local k row
    const int cq = (t & 3) * 16;         // col quarter
    #pragma unroll
    for (int i = 0; i < 4; ++i) {
        float4 v = *(const float4*)&y[(size_t)(b * 64 + kl) * 64 + cq + i * 4];
        float vv[4] = {v.x, v.y, v.z, v.w};
        #pragma unroll
        for (int j = 0; j < 4; ++j) {
            int c = cq + i * 4 + j;
            f16 h = (f16)vv[j];
            float r = vv[j] - (float)h;
            hb[c][kl] = h;
            lb[c][kl] = (f16)r;
        }
    }
    __syncthreads();
    const int c = t >> 2;                // col 0..63
    const int kq = (t & 3) * 16;         // local k base (2 slots)
    #pragma unroll
    for (int s2 = 0; s2 < 2; ++s2) {
        int slot = (kq >> 3) + s2;
        int dslot = slot ^ (c & 7);
        f16x8 hv, lv;
        #pragma unroll
        for (int j = 0; j < 8; ++j) { hv[j] = hb[c][kq + s2 * 8 + j]; lv[j] = lb[c][kq + s2 * 8 + j]; }
        *(f16x8*)&yhT[(size_t)c * NN + b * 64 + dslot * 8] = hv;
        *(f16x8*)&ylT[(size_t)c * NN + b * 64 + dslot * 8] = lv;
    }
}

// ---------------- GEMM: z += K @ y, f16-split MFMA, DIRECT-A (no A LDS) -----------
// BM=128, BK=64, split-K=8, tile stagger. 4 waves; wave w owns rows [w*32,w*32+32)
// -> A fragments are wave-private: load straight global->VGPR (2 dwordx4 per
// 16x16x32 frag), convert f32->f16 hi/lo in-register, feed MFMA. Only Y (shared)
// stays in LDS (16KB dbuf). 32KB LDS + VGPR cap 128 -> 4 blocks/CU (was 2).
// One barrier/tile; counted vmcnt(8) keeps next A-tile loads in flight (T4).
__device__ inline void gload16(const void* g, void* l) {
    __builtin_amdgcn_global_load_lds((const __attribute__((address_space(1))) void*)g,
                                     (__attribute__((address_space(3))) void*)l, 16, 0, 0);
}

__global__ __launch_bounds__(256, 4) void gemm_kernel(const float* __restrict__ A,
                                                      const f16* __restrict__ yhT,
                                                      const f16* __restrict__ ylT,
                                                      float* __restrict__ z) {
    __shared__ char lds[32768];          // Y double buffer: [buf][hi 8K | lo 8K]
    const int t = threadIdx.x;
    const int w = t >> 6;
    const int l = t & 63;
    const size_t row0 = (size_t)blockIdx.x * 128;
    const int kbase = blockIdx.y * 2048;
    const int stag = (blockIdx.x + blockIdx.y * 4) & 31;

    f32x4 acc[2][4];
    #pragma unroll
    for (int m = 0; m < 2; ++m)
        #pragma unroll
        for (int n = 0; n < 4; ++n)
            acc[m][n] = (f32x4){0.f, 0.f, 0.f, 0.f};

    const int ycr = l >> 3;              // + i*8 -> yT row
    const int yco = (l & 7) * 8;         // f16 col in 64-k chunk
    // per-lane A base: row = row0 + w*32 + (l&15), k-lane-offset (l>>4)*8
    const float* abase = A + (row0 + w * 32 + (l & 15)) * 16384 + (l >> 4) * 8;

    float4 rA[2][2][2], rB[2][2][2];     // [m][s][half] raw f32 frags

    auto tmap = [&](int tile) { return (stag + tile) & 31; };

    auto loadA = [&](float4 (&dst)[2][2][2], int tile) {
        const int kt = kbase + tmap(tile) * 64;
        #pragma unroll
        for (int m = 0; m < 2; ++m)
            #pragma unroll
            for (int s = 0; s < 2; ++s) {
                const float* p = abase + (size_t)m * 16 * 16384 + kt + s * 32;
                dst[m][s][0] = *(const float4*)p;
                dst[m][s][1] = *(const float4*)(p + 4);
            }
    };
    auto issueY = [&](int tile, int buf) {
        const int kt = kbase + tmap(tile) * 64;
        #pragma unroll
        for (int j = 0; j < 2; ++j) {
            const int i = 2 * w + j;     // wave-uniform chunk 0..7
            gload16(yhT + (size_t)(i * 8 + ycr) * NN + kt + yco,
                    lds + buf * 16384 + i * 1024);
            gload16(ylT + (size_t)(i * 8 + ycr) * NN + kt + yco,
                    lds + buf * 16384 + 8192 + i * 1024);
        }
    };
    auto mfmaTile = [&](const float4 (&raw)[2][2][2], int buf) {
        #pragma unroll
        for (int s = 0; s < 2; ++s) {
            const int slot = s * 4 + (l >> 4);
            f16x8 ah[2], alo[2];
            #pragma unroll
            for (int m = 0; m < 2; ++m) {
                const float vv[8] = {raw[m][s][0].x, raw[m][s][0].y, raw[m][s][0].z, raw[m][s][0].w,
                                     raw[m][s][1].x, raw[m][s][1].y, raw[m][s][1].z, raw[m][s][1].w};
                #pragma unroll
                for (int j = 0; j < 8; ++j) {
                    f16 h = (f16)vv[j];
                    ah[m][j] = h;
                    alo[m][j] = (f16)(vv[j] - (float)h);
                }
            }
            #pragma unroll
            for (int n = 0; n < 4; ++n) {
                const int c = n * 16 + (l & 15);
                const int byte = c * 128 + ((slot ^ (c & 7)) << 4);
                const f16x8 bh = *(const f16x8*)(lds + buf * 16384 + byte);
                const f16x8 bl = *(const f16x8*)(lds + buf * 16384 + 8192 + byte);
                #pragma unroll
                for (int m = 0; m < 2; ++m) {
                    acc[m][n] = __builtin_amdgcn_mfma_f32_16x16x32_f16(ah[m],  bh, acc[m][n], 0, 0, 0);
                    acc[m][n] = __builtin_amdgcn_mfma_f32_16x16x32_f16(ah[m],  bl, acc[m][n], 0, 0, 0);
                    acc[m][n] = __builtin_amdgcn_mfma_f32_16x16x32_f16(alo[m], bh, acc[m][n], 0, 0, 0);
                }
            }
        }
    };

    // ---- prologue: A(0)->rA, Y(0)->LDS, A(1)->rB; retire rA+Y0, keep rB in flight
    loadA(rA, 0); MEMB;
    issueY(0, 0); MEMB;
    loadA(rB, 1); MEMB;
    asm volatile("s_waitcnt vmcnt(8)" ::: "memory"); SCHED0;
    __builtin_amdgcn_s_barrier(); SCHED0;

    // Invariant at iter T top: regs(T) landed, Y[T&1] in LDS; outstanding = A(T+1) (8).
#define GEMM_ITER(TILE, SET)                                                  \
    issueY((TILE) + 1, ((TILE) + 1) & 1); MEMB;                               \
    mfmaTile(SET, (TILE) & 1);                                                \
    MEMB; SCHED0;                                                             \
    loadA(SET, (TILE) + 2); MEMB;         /* refill set for tile T+2 */       \
    asm volatile("s_waitcnt vmcnt(8)" ::: "memory"); SCHED0; /* Y,A(T+1) in */\
    __builtin_amdgcn_s_barrier(); SCHED0;

    for (int tp = 0; tp < 15; ++tp) {
        GEMM_ITER(2 * tp,     rA);
        GEMM_ITER(2 * tp + 1, rB);
    }
#undef GEMM_ITER
    // ---- tile 30 (no A prefetch) ----
    issueY(31, 1); MEMB;
    mfmaTile(rA, 0);
    MEMB; SCHED0;
    asm volatile("s_waitcnt vmcnt(0)" ::: "memory"); SCHED0;
    __builtin_amdgcn_s_barrier(); SCHED0;
    // ---- tile 31 ----
    mfmaTile(rB, 1);

    // --- epilogue: C/D layout col=l&15, row=(l>>4)*4+q ---
    #pragma unroll
    for (int m = 0; m < 2; ++m)
        #pragma unroll
        for (int n = 0; n < 4; ++n)
            #pragma unroll
            for (int q = 0; q < 4; ++q) {
                const size_t gr = row0 + w * 32 + m * 16 + (l >> 4) * 4 + q;
                const int gc = n * 16 + (l & 15);
                atomicAdd(&z[gr * 64 + gc], acc[m][n][q]);
            }
}

extern "C" void kernel_launch(void* const* d_in, const int* in_sizes, int n_in,
                              void* d_out, int out_size, void* d_ws, size_t ws_size,
                              hipStream_t stream) {
    const float* ytrue = (const float*)d_in[0];
    const float* Kmat  = (const float*)d_in[1];
    const int*   eidx  = (const int*)d_in[2];
    const int* esrc = eidx;
    const int* edst = eidx + NE;
    float* out = (float*)d_out;

    char* ws = (char*)d_ws;
    size_t off = 0;
    auto alloc = [&](size_t bytes) -> void* {
        void* p = ws + off;
        off += (bytes + 255) & ~(size_t)255;
        return p;
    };
    const size_t CSR_ENTRIES = (size_t)NE + 16 * NN;   // padded rows (x16)
    unsigned* deg    = (unsigned*)alloc((size_t)NN * 4);
    unsigned* rowoff = (unsigned*)alloc((size_t)(NN + 1) * 4);
    unsigned* cursor = (unsigned*)alloc((size_t)NN * 4);
    float*    dinv   = (float*)alloc((size_t)NN * 4);
    int2*     csr    = (int2*)alloc(CSR_ENTRIES * 8);
    float*    yA     = (float*)alloc((size_t)NN * NC * 4);
    float*    yB     = (float*)alloc((size_t)NN * NC * 4);
    f16*      yhT    = (f16*)alloc((size_t)NC * NN * 2);
    f16*      ylT    = (f16*)alloc((size_t)NC * NN * 2);

    // --- build normalized padded CSR ---
    hipMemsetAsync(deg, 0, (size_t)NN * 4, stream);
    hipMemsetAsync(csr, 0, CSR_ENTRIES * 8, stream);   // zero-weight pads
    deg_kernel<<<NE / 256, 256, 0, stream>>>(edst, deg);
    scan_kernel<<<1, 1024, 0, stream>>>(deg, dinv, rowoff, cursor);
    fill_kernel<<<NE / 256, 256, 0, stream>>>(esrc, edst, dinv, cursor, csr);

    // --- phase 1: 10 prop steps ---
    const float* cur = ytrue;
    float* bufs[2] = {yA, yB};
    int pb = 0;
    for (int s = 0; s < KSTEPS; ++s) {
        float* nxt = bufs[pb];
        pb ^= 1;
        prop_kernel<<<NN / 4, 256, 0, stream>>>(cur, nxt, rowoff, (const int*)csr);
        cur = nxt;
    }

    // --- split + transpose + swizzle y ---
    ysplit_kernel<<<NN / 64, 256, 0, stream>>>(cur, yhT, ylT);

    // --- GEMM: z = K @ y ---
    float* z = (cur == yA) ? yB : yA;
    hipMemsetAsync(z, 0, (size_t)NN * NC * 4, stream);
    gemm_kernel<<<dim3(128, 8), 256, 0, stream>>>(Kmat, yhT, ylT, z);

    // --- phase 2: 10 prop steps, last writes d_out ---
    float* other = (z == yA) ? yB : yA;
    const float* c2 = z;
    for (int s = 0; s < KSTEPS; ++s) {
        float* nxt = (s == KSTEPS - 1) ? out : other;
        prop_kernel<<<NN / 4, 256, 0, stream>>>(c2, nxt, rowoff, (const int*)csr);
        other = (float*)c2;
        c2 = nxt;
    }
}

// Round 10
// 516.897 us; speedup vs baseline: 1.0654x; 1.0654x over previous
//
#include <hip/hip_runtime.h>

#define NN 16384
#define NC 64
#define NE 524288
#define ALPHA 0.9f
#define KSTEPS 10

typedef _Float16 f16;
typedef _Float16 f16x4 __attribute__((ext_vector_type(4)));
typedef _Float16 f16x8 __attribute__((ext_vector_type(8)));
typedef float f32x4 __attribute__((ext_vector_type(4)));
typedef int i32x16 __attribute__((ext_vector_type(16)));

#define MEMB   asm volatile("" ::: "memory")
#define SCHED0 __builtin_amdgcn_sched_barrier(0)

// ---------------- degree count ----------------
__global__ __launch_bounds__(256) void deg_kernel(const int* __restrict__ dst,
                                                  unsigned* __restrict__ deg) {
    int e = blockIdx.x * 256 + threadIdx.x;
    atomicAdd(&deg[dst[e]], 1u);
}

// ------------- dinv + PADDED exclusive scan + cursor init (single block) -------------
__global__ __launch_bounds__(1024) void scan_kernel(const unsigned* __restrict__ deg,
                                                    float* __restrict__ dinv,
                                                    unsigned* __restrict__ rowoff,
                                                    unsigned* __restrict__ cursor) {
    __shared__ unsigned part[1024];
    const int t = threadIdx.x;
    const int base = t * 16;
    unsigned local[16];
    unsigned s = 0;
    #pragma unroll
    for (int i = 0; i < 16; ++i) {
        local[i] = s;
        s += (deg[base + i] + 15u) & ~15u;
    }
    part[t] = s;
    __syncthreads();
    for (int off = 1; off < 1024; off <<= 1) {
        unsigned v = (t >= off) ? part[t - off] : 0u;
        __syncthreads();
        part[t] += v;
        __syncthreads();
    }
    const unsigned ex = (t == 0) ? 0u : part[t - 1];
    #pragma unroll
    for (int i = 0; i < 16; ++i) {
        unsigned ro = ex + local[i];
        rowoff[base + i] = ro;
        cursor[base + i] = ro;
        unsigned d = deg[base + i];
        dinv[base + i] = rsqrtf(fmaxf((float)d, 1.0f));
    }
    if (t == 1023) rowoff[NN] = part[1023];
}

// ---------------- CSR fill (src, w packed as int2; pads pre-zeroed) ----------------
__global__ __launch_bounds__(256) void fill_kernel(const int* __restrict__ src,
                                                   const int* __restrict__ dst,
                                                   const float* __restrict__ dinv,
                                                   unsigned* __restrict__ cursor,
                                                   int2* __restrict__ csr) {
    int e = blockIdx.x * 256 + threadIdx.x;
    int s = src[e], d = dst[e];
    float w = dinv[s] * dinv[d];
    unsigned p = atomicAdd(&cursor[d], 1u);
    csr[p] = make_int2(s, __float_as_int(w));
}

// ---------------- propagation step: y = a*A@x + (1-a)*x ----------------
// XCD-local node partition: XCD j (= blockIdx&7, round-robin dispatch) owns
// nodes [j*2048,(j+1)*2048) -> its csr slice is ~590KB (8x smaller working
// set) so x (4MB) stays L2-resident and gathers hit L2 instead of L3.
__global__ __launch_bounds__(256) void prop_kernel(const float* __restrict__ x,
                                                   float* __restrict__ y,
                                                   const unsigned* __restrict__ rowoff,
                                                   const int* __restrict__ csr) {
    const int lane = threadIdx.x & 63;
    const int bid = blockIdx.x;
    const int n = __builtin_amdgcn_readfirstlane(((bid & 7) << 11) + ((bid >> 3) << 2)
                                                 + (threadIdx.x >> 6));
    const unsigned beg = rowoff[n];
    const unsigned np = (rowoff[n + 1] - beg) >> 4;   // pairs of 8-edge batches
    float acc0 = 0.f, acc1 = 0.f;
    if (np) {
        i32x16 e0 = *(const i32x16*)(csr + 2 * beg);
        i32x16 e1 = *(const i32x16*)(csr + 2 * beg + 16);
        float xv0[8], xv1[8];
        #pragma unroll
        for (int j = 0; j < 8; ++j) xv0[j] = x[(unsigned)e0[2 * j] * 64u + lane];
        #pragma unroll
        for (int j = 0; j < 8; ++j) xv1[j] = x[(unsigned)e1[2 * j] * 64u + lane];
        for (unsigned p = 1; p < np; ++p) {
            const i32x16 f0 = *(const i32x16*)(csr + 2 * (beg + p * 16));
            const i32x16 f1 = *(const i32x16*)(csr + 2 * (beg + p * 16) + 16);
            #pragma unroll
            for (int j = 0; j < 8; ++j) {
                const float w = __int_as_float(e0[2 * j + 1]);
                if (j & 1) acc1 = fmaf(w, xv0[j], acc1);
                else       acc0 = fmaf(w, xv0[j], acc0);
            }
            #pragma unroll
            for (int j = 0; j < 8; ++j) xv0[j] = x[(unsigned)f0[2 * j] * 64u + lane];
            #pragma unroll
            for (int j = 0; j < 8; ++j) {
                const float w = __int_as_float(e1[2 * j + 1]);
                if (j & 1) acc1 = fmaf(w, xv1[j], acc1);
                else       acc0 = fmaf(w, xv1[j], acc0);
            }
            #pragma unroll
            for (int j = 0; j < 8; ++j) xv1[j] = x[(unsigned)f1[2 * j] * 64u + lane];
            e0 = f0; e1 = f1;
        }
        #pragma unroll
        for (int j = 0; j < 8; ++j) {
            const float w = __int_as_float(e0[2 * j + 1]);
            if (j & 1) acc1 = fmaf(w, xv0[j], acc1);
            else       acc0 = fmaf(w, xv0[j], acc0);
        }
        #pragma unroll
        for (int j = 0; j < 8; ++j) {
            const float w = __int_as_float(e1[2 * j + 1]);
            if (j & 1) acc1 = fmaf(w, xv1[j], acc1);
            else       acc0 = fmaf(w, xv1[j], acc0);
        }
    }
    y[n * 64 + lane] = ALPHA * (acc0 + acc1) + (1.0f - ALPHA) * x[n * 64 + lane];
}

// ---------------- y split: y[16384][64] f32 -> yhT, ylT [64][16384] f16 ----------------
__global__ __launch_bounds__(256) void ysplit_kernel(const float* __restrict__ y,
                                                     f16* __restrict__ yhT,
                                                     f16* __restrict__ ylT) {
    __shared__ f16 hb[64][72];
    __shared__ f16 lb[64][72];
    const int t = threadIdx.x;
    const int b = blockIdx.x;            // k chunk [b*64, b*64+64)
    const int kl = t >> 2;               // local k row
    const int cq = (t & 3) * 16;         // col quarter
    #pragma unroll
    for (int i = 0; i < 4; ++i) {
        float4 v = *(const float4*)&y[(size_t)(b * 64 + kl) * 64 + cq + i * 4];
        float vv[4] = {v.x, v.y, v.z, v.w};
        #pragma unroll
        for (int j = 0; j < 4; ++j) {
            int c = cq + i * 4 + j;
            f16 h = (f16)vv[j];
            float r = vv[j] - (float)h;
            hb[c][kl] = h;
            lb[c][kl] = (f16)r;
        }
    }
    __syncthreads();
    const int c = t >> 2;                // col 0..63
    const int kq = (t & 3) * 16;         // local k base (2 slots)
    #pragma unroll
    for (int s2 = 0; s2 < 2; ++s2) {
        int slot = (kq >> 3) + s2;
        int dslot = slot ^ (c & 7);
        f16x8 hv, lv;
        #pragma unroll
        for (int j = 0; j < 8; ++j) { hv[j] = hb[c][kq + s2 * 8 + j]; lv[j] = lb[c][kq + s2 * 8 + j]; }
        *(f16x8*)&yhT[(size_t)c * NN + b * 64 + dslot * 8] = hv;
        *(f16x8*)&ylT[(size_t)c * NN + b * 64 + dslot * 8] = lv;
    }
}

// ---------------- GEMM: z += K @ y via f16 split MFMA, depth-2 + stagger (R7) ----
__device__ inline void gload16(const void* g, void* l) {
    __builtin_amdgcn_global_load_lds((const __attribute__((address_space(1))) void*)g,
                                     (__attribute__((address_space(3))) void*)l, 16, 0, 0);
}

#define AH_OFF 0
#define AL_OFF 16384
#define YP_OFF 32768   // + cur*16384; YL at +8192

__global__ __launch_bounds__(256, 2) void gemm_kernel(const float* __restrict__ A,
                                                      const f16* __restrict__ yhT,
                                                      const f16* __restrict__ ylT,
                                                      float* __restrict__ z) {
    __shared__ char lds[65536];
    const int t = threadIdx.x;
    const int w = t >> 6;
    const int l = t & 63;
    const size_t row0 = (size_t)blockIdx.x * 128;
    const int kbase = blockIdx.y * 2048;
    const int stag = (blockIdx.x + blockIdx.y * 4) & 31;   // per-block tile rotation

    f32x4 acc[2][4];
    #pragma unroll
    for (int m = 0; m < 2; ++m)
        #pragma unroll
        for (int n = 0; n < 4; ++n)
            acc[m][n] = (f32x4){0.f, 0.f, 0.f, 0.f};

    const int arow_l = w * 4 + (l >> 4);   // + i*16 -> tile row
    const int acol = (l & 15) * 4;         // f32 col in tile
    const int ycr = l >> 3;                // + i*8 -> yT row
    const int yco = (l & 7) * 8;           // f16 col in 64-k chunk

    float4 aA[8], aB[8];

    auto tmap = [&](int tile) { return (stag + tile) & 31; };

    auto loadA = [&](float4 (&dst)[8], int tile) {
        const int kt = kbase + tmap(tile) * 64;
        #pragma unroll
        for (int i = 0; i < 8; ++i)
            dst[i] = *(const float4*)&A[(row0 + i * 16 + arow_l) * 16384 + kt + acol];
    };
    auto issueY = [&](int tile, int cur) {
        const int kt = kbase + tmap(tile) * 64;
        #pragma unroll
        for (int j = 0; j < 2; ++j) {
            const int i = 2 * w + j;   // wave-uniform chunk 0..7
            gload16(yhT + (size_t)(i * 8 + ycr) * NN + kt + yco,
                    lds + YP_OFF + cur * 16384 + i * 1024);
            gload16(ylT + (size_t)(i * 8 + ycr) * NN + kt + yco,
                    lds + YP_OFF + cur * 16384 + 8192 + i * 1024);
        }
    };
    auto writeA = [&](const float4 (&src)[8]) {
        #pragma unroll
        for (int i = 0; i < 8; ++i) {
            const int r = i * 16 + arow_l;
            float v[4] = {src[i].x, src[i].y, src[i].z, src[i].w};
            f16x4 h4, l4;
            #pragma unroll
            for (int j = 0; j < 4; ++j) {
                f16 h = (f16)v[j];
                h4[j] = h;
                l4[j] = (f16)(v[j] - (float)h);
            }
            const int byte = r * 128 + (((((l & 15) >> 1)) ^ (r & 7)) << 4) + (l & 1) * 8;
            *(f16x4*)(lds + AH_OFF + byte) = h4;
            *(f16x4*)(lds + AL_OFF + byte) = l4;
        }
    };
    auto mfmaTile = [&](int cur) {
        #pragma unroll
        for (int s = 0; s < 2; ++s) {
            const int slot = s * 4 + (l >> 4);
            f16x8 ah[2], alo[2];
            #pragma unroll
            for (int m = 0; m < 2; ++m) {
                const int r = w * 32 + m * 16 + (l & 15);
                const int byte = r * 128 + ((slot ^ (r & 7)) << 4);
                ah[m]  = *(const f16x8*)(lds + AH_OFF + byte);
                alo[m] = *(const f16x8*)(lds + AL_OFF + byte);
            }
            #pragma unroll
            for (int n = 0; n < 4; ++n) {
                const int c = n * 16 + (l & 15);
                const int byte = c * 128 + ((slot ^ (c & 7)) << 4);
                const f16x8 bh = *(const f16x8*)(lds + YP_OFF + cur * 16384 + byte);
                const f16x8 bl = *(const f16x8*)(lds + YP_OFF + cur * 16384 + 8192 + byte);
                #pragma unroll
                for (int m = 0; m < 2; ++m) {
                    acc[m][n] = __builtin_amdgcn_mfma_f32_16x16x32_f16(ah[m],  bh, acc[m][n], 0, 0, 0);
                    acc[m][n] = __builtin_amdgcn_mfma_f32_16x16x32_f16(ah[m],  bl, acc[m][n], 0, 0, 0);
                    acc[m][n] = __builtin_amdgcn_mfma_f32_16x16x32_f16(alo[m], bh, acc[m][n], 0, 0, 0);
                }
            }
        }
    };

    // ---- prologue: A(0)->regs->LDS, A(1)->regs, Y(0)->LDS ----
    loadA(aA, 0); MEMB;
    issueY(0, 0); MEMB;
    loadA(aB, 1); MEMB;
    writeA(aA);                                     // compiler waits aA (vmcnt 12)
    asm volatile("s_waitcnt vmcnt(8)" ::: "memory");  SCHED0;  // retire Y(0)
    asm volatile("s_waitcnt lgkmcnt(0)" ::: "memory"); SCHED0;
    __builtin_amdgcn_s_barrier(); SCHED0;

    // per-iteration invariant at top: A-lds = tile T, Y[T&1] ready,
    // SETW regs hold raw A(T+1) (in flight), outstanding vmem = those 8 loads.
#define GEMM_ITER(TILE, CUR, SETF, SETW)                                      \
    issueY((TILE) + 1, (CUR) ^ 1); MEMB;                                      \
    loadA(SETF, (TILE) + 2); MEMB;                                            \
    mfmaTile(CUR);                                                            \
    MEMB; SCHED0;                                                             \
    __builtin_amdgcn_s_barrier();                /* all waves done reading */ \
    writeA(SETW);                                /* waits SETW (vmcnt 12) */  \
    asm volatile("s_waitcnt vmcnt(8)" ::: "memory");  SCHED0; /* Y landed */  \
    asm volatile("s_waitcnt lgkmcnt(0)" ::: "memory"); SCHED0;                \
    __builtin_amdgcn_s_barrier(); SCHED0;

    for (int tp = 0; tp < 15; ++tp) {
        const int t0 = 2 * tp;
        GEMM_ITER(t0,     0, aA, aB);
        GEMM_ITER(t0 + 1, 1, aB, aA);
    }
    // ---- tile 30 (no more A prefetch) ----
    issueY(31, 1); MEMB;
    mfmaTile(0);
    MEMB; SCHED0;
    __builtin_amdgcn_s_barrier();
    writeA(aB);                                   // tile 31
    asm volatile("s_waitcnt vmcnt(0)" ::: "memory");  SCHED0;
    asm volatile("s_waitcnt lgkmcnt(0)" ::: "memory"); SCHED0;
    __builtin_amdgcn_s_barrier(); SCHED0;
    // ---- tile 31 ----
    mfmaTile(1);
#undef GEMM_ITER

    // --- epilogue: C/D layout col=l&15, row=(l>>4)*4+q ---
    #pragma unroll
    for (int m = 0; m < 2; ++m)
        #pragma unroll
        for (int n = 0; n < 4; ++n)
            #pragma unroll
            for (int q = 0; q < 4; ++q) {
                const size_t gr = row0 + w * 32 + m * 16 + (l >> 4) * 4 + q;
                const int gc = n * 16 + (l & 15);
                atomicAdd(&z[gr * 64 + gc], acc[m][n][q]);
            }
}

extern "C" void kernel_launch(void* const* d_in, const int* in_sizes, int n_in,
                              void* d_out, int out_size, void* d_ws, size_t ws_size,
                              hipStream_t stream) {
    const float* ytrue = (const float*)d_in[0];
    const float* Kmat  = (const float*)d_in[1];
    const int*   eidx  = (const int*)d_in[2];
    const int* esrc = eidx;
    const int* edst = eidx + NE;
    float* out = (float*)d_out;

    char* ws = (char*)d_ws;
    size_t off = 0;
    auto alloc = [&](size_t bytes) -> void* {
        void* p = ws + off;
        off += (bytes + 255) & ~(size_t)255;
        return p;
    };
    const size_t CSR_ENTRIES = (size_t)NE + 16 * NN;   // padded rows (x16)
    unsigned* deg    = (unsigned*)alloc((size_t)NN * 4);
    unsigned* rowoff = (unsigned*)alloc((size_t)(NN + 1) * 4);
    unsigned* cursor = (unsigned*)alloc((size_t)NN * 4);
    float*    dinv   = (float*)alloc((size_t)NN * 4);
    int2*     csr    = (int2*)alloc(CSR_ENTRIES * 8);
    float*    yA     = (float*)alloc((size_t)NN * NC * 4);
    float*    yB     = (float*)alloc((size_t)NN * NC * 4);
    f16*      yhT    = (f16*)alloc((size_t)NC * NN * 2);
    f16*      ylT    = (f16*)alloc((size_t)NC * NN * 2);

    // --- build normalized padded CSR ---
    hipMemsetAsync(deg, 0, (size_t)NN * 4, stream);
    hipMemsetAsync(csr, 0, CSR_ENTRIES * 8, stream);   // zero-weight pads
    deg_kernel<<<NE / 256, 256, 0, stream>>>(edst, deg);
    scan_kernel<<<1, 1024, 0, stream>>>(deg, dinv, rowoff, cursor);
    fill_kernel<<<NE / 256, 256, 0, stream>>>(esrc, edst, dinv, cursor, csr);

    // --- phase 1: 10 prop steps ---
    const float* cur = ytrue;
    float* bufs[2] = {yA, yB};
    int pb = 0;
    for (int s = 0; s < KSTEPS; ++s) {
        float* nxt = bufs[pb];
        pb ^= 1;
        prop_kernel<<<NN / 4, 256, 0, stream>>>(cur, nxt, rowoff, (const int*)csr);
        cur = nxt;
    }

    // --- split + transpose + swizzle y ---
    ysplit_kernel<<<NN / 64, 256, 0, stream>>>(cur, yhT, ylT);

    // --- GEMM: z = K @ y ---
    float* z = (cur == yA) ? yB : yA;
    hipMemsetAsync(z, 0, (size_t)NN * NC * 4, stream);
    gemm_kernel<<<dim3(128, 8), 256, 0, stream>>>(Kmat, yhT, ylT, z);

    // --- phase 2: 10 prop steps, last writes d_out ---
    float* other = (z == yA) ? yB : yA;
    const float* c2 = z;
    for (int s = 0; s < KSTEPS; ++s) {
        float* nxt = (s == KSTEPS - 1) ? out : other;
        prop_kernel<<<NN / 4, 256, 0, stream>>>(c2, nxt, rowoff, (const int*)csr);
        other = (float*)c2;
        c2 = nxt;
    }
}